// Round 11
// baseline (844.562 us; speedup 1.0000x reference)
//
#include <hip/hip_runtime.h>
#include <hip/hip_bf16.h>

typedef __hip_bfloat16 bf16;

#define IN_C 128
#define NB 4  // src buckets for pass-1 cache blocking

__device__ inline unsigned short f2bf(float f) {
  bf16 b = __float2bfloat16(f);
  return __builtin_bit_cast(unsigned short, b);
}

// ---- dtype detection ----
__global__ __launch_bounds__(256) void detect_k(const unsigned short* __restrict__ xb,
                                                int* __restrict__ flag) {
  __shared__ int s_sane;
  if (threadIdx.x == 0) s_sane = 0;
  __syncthreads();
  int sane = 0;
  for (int i = threadIdx.x; i < 4096; i += 256) {
    unsigned short h = xb[2 * i];
    int e = (h >> 7) & 0xFF;
    if (e >= 100 && e <= 150) sane++;
  }
  atomicAdd(&s_sane, sane);
  __syncthreads();
  if (threadIdx.x == 0) *flag = (s_sane > 3072) ? 1 : 0;
}

__global__ __launch_bounds__(256) void cvt_k(const void* __restrict__ in,
                                             float* __restrict__ out, int n,
                                             const int* __restrict__ flag) {
  int i = blockIdx.x * 256 + threadIdx.x;
  if (i >= n) return;
  if (*flag) out[i] = __bfloat162float(((const bf16*)in)[i]);
  else       out[i] = ((const float*)in)[i];
}

struct WArgs { const void* p[14]; int off[15]; };
__global__ __launch_bounds__(256) void cvtw_k(WArgs a, float* __restrict__ out,
                                              const int* __restrict__ flag, int total) {
  int i = blockIdx.x * 256 + threadIdx.x;
  if (i >= total) return;
  int s = 0;
#pragma unroll
  for (int j = 1; j < 14; j++) if (i >= a.off[j]) s = j;
  int loc = i - a.off[s];
  if (*flag) out[i] = __bfloat162float(((const bf16*)a.p[s])[loc]);
  else       out[i] = ((const float*)a.p[s])[loc];
}

__global__ __launch_bounds__(256) void out_k(const float* __restrict__ src,
                                             void* __restrict__ out, int n,
                                             const int* __restrict__ flag) {
  int i = blockIdx.x * 256 + threadIdx.x;
  if (i >= n) return;
  float v = src[i];
  if (*flag) ((bf16*)out)[i] = __float2bfloat16(v);
  else       ((float*)out)[i] = v;
}

// ---- register-tiled linear, LDS-only hot loop ----
// NRM: 0 none; 1 out=bf16 normalized rows; 4 out=bf16 raw, out2=bf16 normalized.
template <int K, int C, int R, int ACT, bool PREB, bool POSTB, int NRM>
__global__ __launch_bounds__(256, 2) void lin_k(const float* __restrict__ x,
                                                const float* __restrict__ W,
                                                const float* __restrict__ preb,
                                                const float* __restrict__ postb,
                                                float* __restrict__ out,
                                                float* __restrict__ out2, int n) {
  constexpr int CG  = C / 4;
  constexpr int RG  = 256 / CG;
  constexpr int RPB = RG * R;
  constexpr int KP  = K + 4;
  constexpr int KC  = (K < 4096 / C) ? K : (4096 / C);
  __shared__ float xs[RPB * KP];
  __shared__ float ws[KC * C];
  const int tid = threadIdx.x;
  const int row0 = blockIdx.x * RPB;

  for (int i = tid; i < RPB * K / 4; i += 256) {
    int r4 = i / (K / 4);
    int kk = (i - r4 * (K / 4)) * 4;
    int row = row0 + r4;
    float4 v = make_float4(0.f, 0.f, 0.f, 0.f);
    if (row < n) v = *(const float4*)&x[(size_t)row * K + kk];
    if (PREB) {
      v.x += preb[kk]; v.y += preb[kk + 1]; v.z += preb[kk + 2]; v.w += preb[kk + 3];
    }
    *(float4*)&xs[r4 * KP + kk] = v;
  }

  const int cg = tid % CG;
  const int g  = tid / CG;
  const int c0 = cg * 4;

  float4 acc[R];
#pragma unroll
  for (int r = 0; r < R; r++) acc[r] = make_float4(0.f, 0.f, 0.f, 0.f);

  for (int kc0 = 0; kc0 < K; kc0 += KC) {
    for (int i = tid; i < KC * C / 4; i += 256) {
      *(float4*)&ws[i * 4] = *(const float4*)&W[(size_t)kc0 * C + i * 4];
    }
    __syncthreads();
#pragma unroll 4
    for (int k = 0; k < KC; k += 4) {
      const float* wb = &ws[k * C + c0];
      float4 w0 = *(const float4*)(wb);
      float4 w1 = *(const float4*)(wb + C);
      float4 w2 = *(const float4*)(wb + 2 * C);
      float4 w3 = *(const float4*)(wb + 3 * C);
#pragma unroll
      for (int r = 0; r < R; r++) {
        float4 xv = *(const float4*)&xs[(r * RG + g) * KP + kc0 + k];
        float4 a = acc[r];
        a.x = fmaf(xv.x, w0.x, a.x); a.y = fmaf(xv.x, w0.y, a.y);
        a.z = fmaf(xv.x, w0.z, a.z); a.w = fmaf(xv.x, w0.w, a.w);
        a.x = fmaf(xv.y, w1.x, a.x); a.y = fmaf(xv.y, w1.y, a.y);
        a.z = fmaf(xv.y, w1.z, a.z); a.w = fmaf(xv.y, w1.w, a.w);
        a.x = fmaf(xv.z, w2.x, a.x); a.y = fmaf(xv.z, w2.y, a.y);
        a.z = fmaf(xv.z, w2.z, a.z); a.w = fmaf(xv.z, w2.w, a.w);
        a.x = fmaf(xv.w, w3.x, a.x); a.y = fmaf(xv.w, w3.y, a.y);
        a.z = fmaf(xv.w, w3.z, a.z); a.w = fmaf(xv.w, w3.w, a.w);
        acc[r] = a;
      }
    }
    __syncthreads();
  }

  float4 pb = make_float4(0.f, 0.f, 0.f, 0.f);
  if (POSTB) pb = *(const float4*)&postb[c0];
#pragma unroll
  for (int r = 0; r < R; r++) {
    int row = row0 + r * RG + g;
    float4 v = acc[r];
    v.x += pb.x; v.y += pb.y; v.z += pb.z; v.w += pb.w;
    if (ACT == 1) {
      v.x = (v.x >= 0.f) ? v.x : 0.01f * v.x; v.y = (v.y >= 0.f) ? v.y : 0.01f * v.y;
      v.z = (v.z >= 0.f) ? v.z : 0.01f * v.z; v.w = (v.w >= 0.f) ? v.w : 0.01f * v.w;
    }
    if (ACT == 2) {
      v.x = fmaxf(v.x, 0.f); v.y = fmaxf(v.y, 0.f);
      v.z = fmaxf(v.z, 0.f); v.w = fmaxf(v.w, 0.f);
    }
    if (NRM == 0) {
      if (row < n) *(float4*)&out[(size_t)row * C + c0] = v;
    } else {
      float ss = v.x * v.x + v.y * v.y + v.z * v.z + v.w * v.w;
#pragma unroll
      for (int o = 1; o < CG; o <<= 1) ss += __shfl_xor(ss, o, CG);
      float inv = 1.0f / fmaxf(sqrtf(ss), 1e-12f);
      if (row < n) {
        ushort4 hn = make_ushort4(f2bf(v.x * inv), f2bf(v.y * inv),
                                  f2bf(v.z * inv), f2bf(v.w * inv));
        if (NRM == 1) {
          *(ushort4*)((bf16*)out + (size_t)row * C + c0) = hn;
        } else {  // NRM == 4
          ushort4 hr = make_ushort4(f2bf(v.x), f2bf(v.y), f2bf(v.z), f2bf(v.w));
          *(ushort4*)((bf16*)out  + (size_t)row * C + c0) = hr;
          *(ushort4*)((bf16*)out2 + (size_t)row * C + c0) = hn;
        }
      }
    }
  }
}

// ---- CSR build over keys (bucket(src)*N + dst), XCD-partitioned atomics ----
__global__ __launch_bounds__(256) void count_k(const int* __restrict__ src,
                                               const int* __restrict__ dst,
                                               int* __restrict__ cnt, int E, int N,
                                               int bdiv) {
  int part = blockIdx.x & 7;
  int lo = (int)(((long)part * N) >> 3);
  int hi = (int)((((long)part + 1) * N) >> 3);
  int tid = (blockIdx.x >> 3) * 256 + threadIdx.x;
  int stride = (gridDim.x >> 3) * 256;
  for (int e = tid; e < E; e += stride) {
    int d = dst[e];
    if (d < lo || d >= hi) continue;
    int b = src[e] / bdiv;
    atomicAdd(&cnt[b * N + d], 1);
  }
}

__global__ __launch_bounds__(256) void scan_local_k(const int* __restrict__ cnt,
                                                    int* __restrict__ off,
                                                    int* __restrict__ part, int n) {
  __shared__ int sd[256];
  int t = threadIdx.x;
  int base = blockIdx.x * 2048 + t * 8;
  int v[8], s = 0;
#pragma unroll
  for (int j = 0; j < 8; j++) {
    int idx = base + j;
    v[j] = (idx < n) ? cnt[idx] : 0;
    s += v[j];
  }
  sd[t] = s;
  __syncthreads();
  for (int o = 1; o < 256; o <<= 1) {
    int x = (t >= o) ? sd[t - o] : 0;
    __syncthreads();
    sd[t] += x;
    __syncthreads();
  }
  int excl = sd[t] - s;
  if (t == 255) part[blockIdx.x] = sd[255];
  int run = excl;
#pragma unroll
  for (int j = 0; j < 8; j++) {
    int idx = base + j;
    if (idx < n) off[idx] = run;
    run += v[j];
  }
}

__global__ __launch_bounds__(256) void scan_add_k(int* __restrict__ off,
                                                  int* __restrict__ cur,
                                                  const int* __restrict__ part,
                                                  int nb, int n) {
  __shared__ int s_pref;
  if (threadIdx.x == 0) {
    int s = 0;
    for (int i = 0; i < (int)blockIdx.x; i++) s += part[i];
    s_pref = s;
    if (blockIdx.x == 0) {
      int tot = 0;
      for (int i = 0; i < nb; i++) tot += part[i];
      off[n] = tot;
    }
  }
  __syncthreads();
  int pref = s_pref;
  int base = blockIdx.x * 2048 + threadIdx.x * 8;
#pragma unroll
  for (int j = 0; j < 8; j++) {
    int idx = base + j;
    if (idx < n) { int val = off[idx] + pref; off[idx] = val; cur[idx] = val; }
  }
}

__global__ __launch_bounds__(256) void fill_k(const int* __restrict__ src,
                                              const int* __restrict__ dst,
                                              int* __restrict__ cur,
                                              int* __restrict__ dl_src, int E, int N,
                                              int bdiv) {
  int part = blockIdx.x & 7;
  int lo = (int)(((long)part * N) >> 3);
  int hi = (int)((((long)part + 1) * N) >> 3);
  int tid = (blockIdx.x >> 3) * 256 + threadIdx.x;
  int stride = (gridDim.x >> 3) * 256;
  for (int e = tid; e < E; e += stride) {
    int d = dst[e];
    if (d < lo || d >= hi) continue;
    int s = src[e];
    int b = s / bdiv;
    int pd = atomicAdd(&cur[b * N + d], 1);
    dl_src[pd] = s;
  }
}

__device__ inline float dot8(uint4 h, float4 r0, float4 r1) {
  float p;
  p  = __uint_as_float(h.x << 16) * r0.x + __uint_as_float(h.x & 0xffff0000u) * r0.y;
  p += __uint_as_float(h.y << 16) * r0.z + __uint_as_float(h.y & 0xffff0000u) * r0.w;
  p += __uint_as_float(h.z << 16) * r1.x + __uint_as_float(h.z & 0xffff0000u) * r1.y;
  p += __uint_as_float(h.w << 16) * r1.z + __uint_as_float(h.w & 0xffff0000u) * r1.w;
  return p;
}

__device__ inline void expand8(uint4 h, float4& r0, float4& r1) {
  r0.x = __uint_as_float(h.x << 16); r0.y = __uint_as_float(h.x & 0xffff0000u);
  r0.z = __uint_as_float(h.y << 16); r0.w = __uint_as_float(h.y & 0xffff0000u);
  r1.x = __uint_as_float(h.z << 16); r1.y = __uint_as_float(h.z & 0xffff0000u);
  r1.z = __uint_as_float(h.w << 16); r1.w = __uint_as_float(h.w & 0xffff0000u);
}

__device__ inline void fma8(uint4 h, float w, float4& a0, float4& a1) {
  a0.x += w * __uint_as_float(h.x << 16); a0.y += w * __uint_as_float(h.x & 0xffff0000u);
  a0.z += w * __uint_as_float(h.y << 16); a0.w += w * __uint_as_float(h.y & 0xffff0000u);
  a1.x += w * __uint_as_float(h.z << 16); a1.y += w * __uint_as_float(h.z & 0xffff0000u);
  a1.z += w * __uint_as_float(h.w << 16); a1.w += w * __uint_as_float(h.w & 0xffff0000u);
}

// ---- pass1, bucket-major: all resident blocks gather from one 3.2MB XLN slice ----
__global__ __launch_bounds__(256) void gat_pre_k(const uint4* __restrict__ XLN,
                                                 const uint4* __restrict__ XRNB,
                                                 const int* __restrict__ off,
                                                 const int* __restrict__ dl_src,
                                                 float* __restrict__ EV,
                                                 float* __restrict__ DEN, int n, int bpb) {
  int b = blockIdx.x / bpb;
  int node = (blockIdx.x - b * bpb) * 4 + (threadIdx.x >> 6);
  if (node >= n) return;
  int lane = threadIdx.x & 63;
  int g = lane >> 3, gl = lane & 7;
  int key = b * n + node;
  int beg = off[key], end = off[key + 1];
  if (beg >= end) return;
  float4 xr0, xr1;
  expand8(XRNB[(size_t)node * 8 + gl], xr0, xr1);
  for (int i0 = beg; i0 < end; i0 += 8) {
    int i = i0 + g;
    int s = dl_src[(i < end) ? i : (end - 1)];
    uint4 h = XLN[(size_t)s * 8 + gl];
    float p = dot8(h, xr0, xr1);
    p += __shfl_xor(p, 1, 8); p += __shfl_xor(p, 2, 8); p += __shfl_xor(p, 4, 8);
    if (gl == 0 && i < end) {
      float ev = __expf(__expf(p) * 4.0f);  // exp(v), v=exp(cos)/TAU
      EV[i] = ev;
      unsafeAtomicAdd(&DEN[s], ev);
    }
  }
}

// ---- pass2: wave per node, walks its NB segments; acc += (ev/den[s])*xlb[s] ----
__global__ __launch_bounds__(256) void gat_dst_k(const uint4* __restrict__ XLB,
                                                 const float* __restrict__ EV,
                                                 const float* __restrict__ DEN,
                                                 const int* __restrict__ off,
                                                 const int* __restrict__ dl_src,
                                                 float* __restrict__ AGG, int n) {
  int wv = threadIdx.x >> 6, lane = threadIdx.x & 63;
  int node = blockIdx.x * 4 + wv;
  if (node >= n) return;
  int g = lane >> 3, gl = lane & 7;
  float4 a0 = {0.f, 0.f, 0.f, 0.f}, a1 = {0.f, 0.f, 0.f, 0.f};
#pragma unroll
  for (int b = 0; b < NB; b++) {
    int key = b * n + node;
    int beg = off[key], end = off[key + 1];
    for (int i0 = beg; i0 < end; i0 += 8) {
      int i = i0 + g;
      int ic = (i < end) ? i : (end - 1);
      int s = dl_src[ic];
      uint4 h = XLB[(size_t)s * 8 + gl];
      float w = 0.f;
      if (gl == 0 && i < end) w = EV[i] / DEN[s];
      w = __shfl(w, 0, 8);
      fma8(h, w, a0, a1);
    }
  }
#pragma unroll
  for (int o = 8; o < 64; o <<= 1) {
    a0.x += __shfl_xor(a0.x, o); a0.y += __shfl_xor(a0.y, o);
    a0.z += __shfl_xor(a0.z, o); a0.w += __shfl_xor(a0.w, o);
    a1.x += __shfl_xor(a1.x, o); a1.y += __shfl_xor(a1.y, o);
    a1.z += __shfl_xor(a1.z, o); a1.w += __shfl_xor(a1.w, o);
  }
  if (g == 0) {
    *(float4*)&AGG[(size_t)node * 64 + gl * 8]     = a0;
    *(float4*)&AGG[(size_t)node * 64 + gl * 8 + 4] = a1;
  }
}

extern "C" void kernel_launch(void* const* d_in, const int* in_sizes, int n_in,
                              void* d_out, int out_size, void* d_ws, size_t ws_size,
                              hipStream_t stream) {
  const int N = in_sizes[0] / IN_C;
  const int E = in_sizes[1] / 2;
  const int* ei  = (const int*)d_in[1];
  const int* src = ei;
  const int* dst = ei + E;
  const int bdiv = (N + NB - 1) / NB;

  char* wsb = (char*)d_ws;
  size_t o = 0;
  auto alloc = [&](size_t elems) { void* p = wsb + o; o += ((elems + 3) & ~3ull) * 4; return p; };
  int*   FLAG   = (int*)alloc(16);
  float* WF     = (float*)alloc(60000);
  int*   CNT    = (int*)alloc((size_t)NB * N);
  int*   OFF    = (int*)alloc((size_t)NB * N + 1);
  int*   CUR    = (int*)alloc((size_t)NB * N);
  int*   PART   = (int*)alloc(256);
  int*   DL_SRC = (int*)alloc(E);
  float* EV     = (float*)alloc(E);
  float* DEN    = (float*)alloc(N);
  uint4* XLB    = (uint4*)alloc((size_t)N * 32);
  uint4* XLN    = (uint4*)alloc((size_t)N * 32);
  uint4* XRNB   = (uint4*)alloc((size_t)N * 32);
  float* bufA   = (float*)alloc((size_t)N * 128);  // XF / OUTF
  float* bufB   = (float*)alloc((size_t)N * 128);  // H0 -> B1 | B2

  float* XF  = bufA;
  float* H0  = bufB;
  float* B1  = bufB;
  float* B2  = bufB + (size_t)N * 64;

  dim3 blk(256);
  auto nblk = [](long total, int per) { return dim3((unsigned)((total + per - 1) / per)); };

  // ---- dtype detect + convert ----
  detect_k<<<1, blk, 0, stream>>>((const unsigned short*)d_in[0], FLAG);
  cvt_k<<<nblk((long)N * 128, 256), blk, 0, stream>>>(d_in[0], XF, N * 128, FLAG);
  WArgs wa;
  int wtot = 0;
  float* wp[16];
  for (int i = 2; i < 16; i++) {
    wa.p[i - 2] = d_in[i];
    wa.off[i - 2] = wtot;
    wp[i] = WF + wtot;
    wtot += in_sizes[i];
  }
  wa.off[14] = wtot;
  cvtw_k<<<nblk(wtot, 256), blk, 0, stream>>>(wa, WF, FLAG, wtot);
  const float *W_in = wp[2], *b_in = wp[3], *Wl1 = wp[4], *Wr1 = wp[5],
              *bias1 = wp[6], *Wc1 = wp[7], *Wl2 = wp[8], *Wr2 = wp[9],
              *bias2 = wp[10], *Wc2 = wp[11], *W3 = wp[12], *b3 = wp[13],
              *W4 = wp[14], *b4 = wp[15];

  // ---- bucketed CSR build ----
  hipMemsetAsync(CNT, 0, sizeof(int) * (size_t)NB * N, stream);
  count_k<<<dim3(2048), blk, 0, stream>>>(src, dst, CNT, E, N, bdiv);
  {
    int nkeys = NB * N;
    int nb = (nkeys + 2047) / 2048;
    scan_local_k<<<dim3(nb), blk, 0, stream>>>(CNT, OFF, PART, nkeys);
    scan_add_k<<<dim3(nb), blk, 0, stream>>>(OFF, CUR, PART, nb, nkeys);
  }
  fill_k<<<dim3(2048), blk, 0, stream>>>(src, dst, CUR, DL_SRC, E, N, bdiv);

  const int bpb = (N + 3) / 4;  // blocks per bucket in pass1

  // h0 = leaky(x @ W_in + b_in)
  lin_k<128, 128, 8, 1, false, true, 0>
      <<<nblk(N, 64), blk, 0, stream>>>(XF, W_in, nullptr, b_in, H0, nullptr, N);

  // ---- GAT layer 1 ----
  lin_k<128, 64, 4, 0, false, false, 4>
      <<<nblk(N, 64), blk, 0, stream>>>(H0, Wl1, nullptr, nullptr, (float*)XLB, (float*)XLN, N);
  lin_k<128, 64, 4, 0, false, false, 1>
      <<<nblk(N, 64), blk, 0, stream>>>(H0, Wr1, nullptr, nullptr, (float*)XRNB, nullptr, N);
  hipMemsetAsync(DEN, 0, sizeof(float) * (size_t)N, stream);
  gat_pre_k<<<dim3(NB * bpb), blk, 0, stream>>>(XLN, XRNB, OFF, DL_SRC, EV, DEN, N, bpb);
  gat_dst_k<<<nblk(N, 4), blk, 0, stream>>>(XLB, EV, DEN, OFF, DL_SRC, B1, N);
  lin_k<64, 64, 8, 1, true, false, 0>
      <<<nblk(N, 128), blk, 0, stream>>>(B1, Wc1, bias1, nullptr, B1, nullptr, N);

  // ---- GAT layer 2 ----
  lin_k<64, 64, 8, 0, false, false, 4>
      <<<nblk(N, 128), blk, 0, stream>>>(B1, Wl2, nullptr, nullptr, (float*)XLB, (float*)XLN, N);
  lin_k<64, 64, 8, 0, false, false, 1>
      <<<nblk(N, 128), blk, 0, stream>>>(B1, Wr2, nullptr, nullptr, (float*)XRNB, nullptr, N);
  hipMemsetAsync(DEN, 0, sizeof(float) * (size_t)N, stream);
  gat_pre_k<<<dim3(NB * bpb), blk, 0, stream>>>(XLN, XRNB, OFF, DL_SRC, EV, DEN, N, bpb);
  gat_dst_k<<<nblk(N, 4), blk, 0, stream>>>(XLB, EV, DEN, OFF, DL_SRC, B2, N);
  lin_k<64, 64, 8, 1, true, false, 0>
      <<<nblk(N, 128), blk, 0, stream>>>(B2, Wc2, bias2, nullptr, B2, nullptr, N);

  // ---- head ----
  lin_k<64, 64, 8, 2, false, true, 0>
      <<<nblk(N, 128), blk, 0, stream>>>(B2, W3, nullptr, b3, B1, nullptr, N);
  lin_k<64, 32, 4, 0, false, true, 0>
      <<<nblk(N, 128), blk, 0, stream>>>(B1, W4, nullptr, b4, bufA, nullptr, N);
  out_k<<<nblk((long)N * 32, 256), blk, 0, stream>>>(bufA, d_out, N * 32, FLAG);
}

// Round 12
// 781.099 us; speedup vs baseline: 1.0812x; 1.0812x over previous
//
#include <hip/hip_runtime.h>
#include <hip/hip_bf16.h>

typedef __hip_bfloat16 bf16;

#define IN_C 128
#define NB 4  // src buckets for cache blocking

__device__ inline unsigned short f2bf(float f) {
  bf16 b = __float2bfloat16(f);
  return __builtin_bit_cast(unsigned short, b);
}

// ---- dtype detection ----
__global__ __launch_bounds__(256) void detect_k(const unsigned short* __restrict__ xb,
                                                int* __restrict__ flag) {
  __shared__ int s_sane;
  if (threadIdx.x == 0) s_sane = 0;
  __syncthreads();
  int sane = 0;
  for (int i = threadIdx.x; i < 4096; i += 256) {
    unsigned short h = xb[2 * i];
    int e = (h >> 7) & 0xFF;
    if (e >= 100 && e <= 150) sane++;
  }
  atomicAdd(&s_sane, sane);
  __syncthreads();
  if (threadIdx.x == 0) *flag = (s_sane > 3072) ? 1 : 0;
}

__global__ __launch_bounds__(256) void cvt_k(const void* __restrict__ in,
                                             float* __restrict__ out, int n,
                                             const int* __restrict__ flag) {
  int i = blockIdx.x * 256 + threadIdx.x;
  if (i >= n) return;
  if (*flag) out[i] = __bfloat162float(((const bf16*)in)[i]);
  else       out[i] = ((const float*)in)[i];
}

struct WArgs { const void* p[14]; int off[15]; };
__global__ __launch_bounds__(256) void cvtw_k(WArgs a, float* __restrict__ out,
                                              const int* __restrict__ flag, int total) {
  int i = blockIdx.x * 256 + threadIdx.x;
  if (i >= total) return;
  int s = 0;
#pragma unroll
  for (int j = 1; j < 14; j++) if (i >= a.off[j]) s = j;
  int loc = i - a.off[s];
  if (*flag) out[i] = __bfloat162float(((const bf16*)a.p[s])[loc]);
  else       out[i] = ((const float*)a.p[s])[loc];
}

__global__ __launch_bounds__(256) void out_k(const float* __restrict__ src,
                                             void* __restrict__ out, int n,
                                             const int* __restrict__ flag) {
  int i = blockIdx.x * 256 + threadIdx.x;
  if (i >= n) return;
  float v = src[i];
  if (*flag) ((bf16*)out)[i] = __float2bfloat16(v);
  else       ((float*)out)[i] = v;
}

// ---- register-tiled linear, LDS-only hot loop ----
template <int K, int C, int R, int ACT, bool PREB, bool POSTB, int NRM>
__global__ __launch_bounds__(256, 2) void lin_k(const float* __restrict__ x,
                                                const float* __restrict__ W,
                                                const float* __restrict__ preb,
                                                const float* __restrict__ postb,
                                                float* __restrict__ out,
                                                float* __restrict__ out2, int n) {
  constexpr int CG  = C / 4;
  constexpr int RG  = 256 / CG;
  constexpr int RPB = RG * R;
  constexpr int KP  = K + 4;
  constexpr int KC  = (K < 4096 / C) ? K : (4096 / C);
  __shared__ float xs[RPB * KP];
  __shared__ float ws[KC * C];
  const int tid = threadIdx.x;
  const int row0 = blockIdx.x * RPB;

  for (int i = tid; i < RPB * K / 4; i += 256) {
    int r4 = i / (K / 4);
    int kk = (i - r4 * (K / 4)) * 4;
    int row = row0 + r4;
    float4 v = make_float4(0.f, 0.f, 0.f, 0.f);
    if (row < n) v = *(const float4*)&x[(size_t)row * K + kk];
    if (PREB) {
      v.x += preb[kk]; v.y += preb[kk + 1]; v.z += preb[kk + 2]; v.w += preb[kk + 3];
    }
    *(float4*)&xs[r4 * KP + kk] = v;
  }

  const int cg = tid % CG;
  const int g  = tid / CG;
  const int c0 = cg * 4;

  float4 acc[R];
#pragma unroll
  for (int r = 0; r < R; r++) acc[r] = make_float4(0.f, 0.f, 0.f, 0.f);

  for (int kc0 = 0; kc0 < K; kc0 += KC) {
    for (int i = tid; i < KC * C / 4; i += 256) {
      *(float4*)&ws[i * 4] = *(const float4*)&W[(size_t)kc0 * C + i * 4];
    }
    __syncthreads();
#pragma unroll 4
    for (int k = 0; k < KC; k += 4) {
      const float* wb = &ws[k * C + c0];
      float4 w0 = *(const float4*)(wb);
      float4 w1 = *(const float4*)(wb + C);
      float4 w2 = *(const float4*)(wb + 2 * C);
      float4 w3 = *(const float4*)(wb + 3 * C);
#pragma unroll
      for (int r = 0; r < R; r++) {
        float4 xv = *(const float4*)&xs[(r * RG + g) * KP + kc0 + k];
        float4 a = acc[r];
        a.x = fmaf(xv.x, w0.x, a.x); a.y = fmaf(xv.x, w0.y, a.y);
        a.z = fmaf(xv.x, w0.z, a.z); a.w = fmaf(xv.x, w0.w, a.w);
        a.x = fmaf(xv.y, w1.x, a.x); a.y = fmaf(xv.y, w1.y, a.y);
        a.z = fmaf(xv.y, w1.z, a.z); a.w = fmaf(xv.y, w1.w, a.w);
        a.x = fmaf(xv.z, w2.x, a.x); a.y = fmaf(xv.z, w2.y, a.y);
        a.z = fmaf(xv.z, w2.z, a.z); a.w = fmaf(xv.z, w2.w, a.w);
        a.x = fmaf(xv.w, w3.x, a.x); a.y = fmaf(xv.w, w3.y, a.y);
        a.z = fmaf(xv.w, w3.z, a.z); a.w = fmaf(xv.w, w3.w, a.w);
        acc[r] = a;
      }
    }
    __syncthreads();
  }

  float4 pb = make_float4(0.f, 0.f, 0.f, 0.f);
  if (POSTB) pb = *(const float4*)&postb[c0];
#pragma unroll
  for (int r = 0; r < R; r++) {
    int row = row0 + r * RG + g;
    float4 v = acc[r];
    v.x += pb.x; v.y += pb.y; v.z += pb.z; v.w += pb.w;
    if (ACT == 1) {
      v.x = (v.x >= 0.f) ? v.x : 0.01f * v.x; v.y = (v.y >= 0.f) ? v.y : 0.01f * v.y;
      v.z = (v.z >= 0.f) ? v.z : 0.01f * v.z; v.w = (v.w >= 0.f) ? v.w : 0.01f * v.w;
    }
    if (ACT == 2) {
      v.x = fmaxf(v.x, 0.f); v.y = fmaxf(v.y, 0.f);
      v.z = fmaxf(v.z, 0.f); v.w = fmaxf(v.w, 0.f);
    }
    if (NRM == 0) {
      if (row < n) *(float4*)&out[(size_t)row * C + c0] = v;
    } else {
      float ss = v.x * v.x + v.y * v.y + v.z * v.z + v.w * v.w;
#pragma unroll
      for (int o = 1; o < CG; o <<= 1) ss += __shfl_xor(ss, o, CG);
      float inv = 1.0f / fmaxf(sqrtf(ss), 1e-12f);
      if (row < n) {
        ushort4 hn = make_ushort4(f2bf(v.x * inv), f2bf(v.y * inv),
                                  f2bf(v.z * inv), f2bf(v.w * inv));
        if (NRM == 1) {
          *(ushort4*)((bf16*)out + (size_t)row * C + c0) = hn;
        } else {  // NRM == 4
          ushort4 hr = make_ushort4(f2bf(v.x), f2bf(v.y), f2bf(v.z), f2bf(v.w));
          *(ushort4*)((bf16*)out  + (size_t)row * C + c0) = hr;
          *(ushort4*)((bf16*)out2 + (size_t)row * C + c0) = hn;
        }
      }
    }
  }
}

// ---- CSR build over keys (bucket(src)*N + dst), XCD-partitioned atomics ----
__global__ __launch_bounds__(256) void count_k(const int* __restrict__ src,
                                               const int* __restrict__ dst,
                                               int* __restrict__ cnt, int E, int N,
                                               int bdiv) {
  int part = blockIdx.x & 7;
  int lo = (int)(((long)part * N) >> 3);
  int hi = (int)((((long)part + 1) * N) >> 3);
  int tid = (blockIdx.x >> 3) * 256 + threadIdx.x;
  int stride = (gridDim.x >> 3) * 256;
  for (int e = tid; e < E; e += stride) {
    int d = dst[e];
    if (d < lo || d >= hi) continue;
    int b = src[e] / bdiv;
    atomicAdd(&cnt[b * N + d], 1);
  }
}

__global__ __launch_bounds__(256) void scan_local_k(const int* __restrict__ cnt,
                                                    int* __restrict__ off,
                                                    int* __restrict__ part, int n) {
  __shared__ int sd[256];
  int t = threadIdx.x;
  int base = blockIdx.x * 2048 + t * 8;
  int v[8], s = 0;
#pragma unroll
  for (int j = 0; j < 8; j++) {
    int idx = base + j;
    v[j] = (idx < n) ? cnt[idx] : 0;
    s += v[j];
  }
  sd[t] = s;
  __syncthreads();
  for (int o = 1; o < 256; o <<= 1) {
    int x = (t >= o) ? sd[t - o] : 0;
    __syncthreads();
    sd[t] += x;
    __syncthreads();
  }
  int excl = sd[t] - s;
  if (t == 255) part[blockIdx.x] = sd[255];
  int run = excl;
#pragma unroll
  for (int j = 0; j < 8; j++) {
    int idx = base + j;
    if (idx < n) off[idx] = run;
    run += v[j];
  }
}

__global__ __launch_bounds__(256) void scan_add_k(int* __restrict__ off,
                                                  int* __restrict__ cur,
                                                  const int* __restrict__ part,
                                                  int nb, int n) {
  __shared__ int s_pref;
  if (threadIdx.x == 0) {
    int s = 0;
    for (int i = 0; i < (int)blockIdx.x; i++) s += part[i];
    s_pref = s;
    if (blockIdx.x == 0) {
      int tot = 0;
      for (int i = 0; i < nb; i++) tot += part[i];
      off[n] = tot;
    }
  }
  __syncthreads();
  int pref = s_pref;
  int base = blockIdx.x * 2048 + threadIdx.x * 8;
#pragma unroll
  for (int j = 0; j < 8; j++) {
    int idx = base + j;
    if (idx < n) { int val = off[idx] + pref; off[idx] = val; cur[idx] = val; }
  }
}

// fill: scatter int2(src,dst) per edge into bucketed-CSR position
__global__ __launch_bounds__(256) void fill_k(const int* __restrict__ src,
                                              const int* __restrict__ dst,
                                              int* __restrict__ cur,
                                              int2* __restrict__ dl, int E, int N,
                                              int bdiv) {
  int part = blockIdx.x & 7;
  int lo = (int)(((long)part * N) >> 3);
  int hi = (int)((((long)part + 1) * N) >> 3);
  int tid = (blockIdx.x >> 3) * 256 + threadIdx.x;
  int stride = (gridDim.x >> 3) * 256;
  for (int e = tid; e < E; e += stride) {
    int d = dst[e];
    if (d < lo || d >= hi) continue;
    int s = src[e];
    int b = s / bdiv;
    int pd = atomicAdd(&cur[b * N + d], 1);
    dl[pd] = make_int2(s, d);
  }
}

__device__ inline void expand8(uint4 h, float4& r0, float4& r1) {
  r0.x = __uint_as_float(h.x << 16); r0.y = __uint_as_float(h.x & 0xffff0000u);
  r0.z = __uint_as_float(h.y << 16); r0.w = __uint_as_float(h.y & 0xffff0000u);
  r1.x = __uint_as_float(h.z << 16); r1.y = __uint_as_float(h.z & 0xffff0000u);
  r1.z = __uint_as_float(h.w << 16); r1.w = __uint_as_float(h.w & 0xffff0000u);
}

__device__ inline float dotbb(uint4 a, uint4 b) {
  float4 a0, a1, b0, b1;
  expand8(a, a0, a1);
  expand8(b, b0, b1);
  return a0.x * b0.x + a0.y * b0.y + a0.z * b0.z + a0.w * b0.w +
         a1.x * b1.x + a1.y * b1.y + a1.z * b1.z + a1.w * b1.w;
}

__device__ inline void fma8(uint4 h, float w, float4& a0, float4& a1) {
  a0.x += w * __uint_as_float(h.x << 16); a0.y += w * __uint_as_float(h.x & 0xffff0000u);
  a0.z += w * __uint_as_float(h.y << 16); a0.w += w * __uint_as_float(h.y & 0xffff0000u);
  a1.x += w * __uint_as_float(h.z << 16); a1.y += w * __uint_as_float(h.z & 0xffff0000u);
  a1.z += w * __uint_as_float(h.w << 16); a1.w += w * __uint_as_float(h.w & 0xffff0000u);
}

// ---- pass1: FLAT edge loop over bucket-sorted edges. 8 lanes/edge, 2x unroll.
// Locality by construction: consecutive edges share the same 3.2MB XLN bucket
// slice (L2) and near-monotonic dst (XRNB in L1).
__global__ __launch_bounds__(256) void gat_pre_k(const uint4* __restrict__ XLN,
                                                 const uint4* __restrict__ XRNB,
                                                 const int2* __restrict__ DL,
                                                 float* __restrict__ EV,
                                                 float* __restrict__ DEN, int E) {
  int gl = threadIdx.x & 7;
  int grp = blockIdx.x * 32 + (threadIdx.x >> 3);
  long stride = (long)gridDim.x * 64;  // 32 groups * 2 edges
  for (long base = (long)grp * 2; base < E; base += stride) {
    int eA = (int)base, eB = eA + 1;
    int2 dA = DL[eA];
    int2 dB = DL[(eB < E) ? eB : eA];
    uint4 sA = XLN[(size_t)dA.x * 8 + gl];
    uint4 rA = XRNB[(size_t)dA.y * 8 + gl];
    uint4 sB = XLN[(size_t)dB.x * 8 + gl];
    uint4 rB = XRNB[(size_t)dB.y * 8 + gl];
    float pA = dotbb(sA, rA);
    float pB = dotbb(sB, rB);
    pA += __shfl_xor(pA, 1, 8); pA += __shfl_xor(pA, 2, 8); pA += __shfl_xor(pA, 4, 8);
    pB += __shfl_xor(pB, 1, 8); pB += __shfl_xor(pB, 2, 8); pB += __shfl_xor(pB, 4, 8);
    if (gl == 0) {
      float evA = __expf(__expf(pA) * 4.0f);  // exp(v), v=exp(cos)/TAU
      EV[eA] = evA;
      unsafeAtomicAdd(&DEN[dA.x], evA);
      if (eB < E) {
        float evB = __expf(__expf(pB) * 4.0f);
        EV[eB] = evB;
        unsafeAtomicAdd(&DEN[dB.x], evB);
      }
    }
  }
}

// ---- pass2: wave/node, work-queue over the node's NB segments (no padding) ----
__global__ __launch_bounds__(256) void gat_dst_k(const uint4* __restrict__ XLB,
                                                 const float* __restrict__ EV,
                                                 const float* __restrict__ DEN,
                                                 const int* __restrict__ off,
                                                 const int2* __restrict__ DL,
                                                 float* __restrict__ AGG, int n) {
  int wv = threadIdx.x >> 6, lane = threadIdx.x & 63;
  int node = blockIdx.x * 4 + wv;
  if (node >= n) return;
  int g = lane >> 3, gl = lane & 7;
  int bg0 = off[0 * n + node], en0 = off[0 * n + node + 1];
  int bg1 = off[1 * n + node], en1 = off[1 * n + node + 1];
  int bg2 = off[2 * n + node], en2 = off[2 * n + node + 1];
  int bg3 = off[3 * n + node], en3 = off[3 * n + node + 1];
  int c1 = en0 - bg0;
  int c2 = c1 + (en1 - bg1);
  int c3 = c2 + (en2 - bg2);
  int deg = c3 + (en3 - bg3);
  float4 a0 = {0.f, 0.f, 0.f, 0.f}, a1 = {0.f, 0.f, 0.f, 0.f};
  for (int t0 = 0; t0 < deg; t0 += 16) {
    int tA = t0 + g * 2, tB = tA + 1;
    int tAc = min(tA, deg - 1), tBc = min(tB, deg - 1);
    int iA = bg0 + tAc;
    if (tAc >= c1) iA = bg1 + tAc - c1;
    if (tAc >= c2) iA = bg2 + tAc - c2;
    if (tAc >= c3) iA = bg3 + tAc - c3;
    int iB = bg0 + tBc;
    if (tBc >= c1) iB = bg1 + tBc - c1;
    if (tBc >= c2) iB = bg2 + tBc - c2;
    if (tBc >= c3) iB = bg3 + tBc - c3;
    int sA = DL[iA].x;
    int sB = DL[iB].x;
    uint4 hA = XLB[(size_t)sA * 8 + gl];
    uint4 hB = XLB[(size_t)sB * 8 + gl];
    float wA = 0.f, wB = 0.f;
    if (gl == 0) {
      if (tA < deg) wA = EV[iA] / DEN[sA];
      if (tB < deg) wB = EV[iB] / DEN[sB];
    }
    wA = __shfl(wA, 0, 8);
    wB = __shfl(wB, 0, 8);
    fma8(hA, wA, a0, a1);
    fma8(hB, wB, a0, a1);
  }
#pragma unroll
  for (int o = 8; o < 64; o <<= 1) {
    a0.x += __shfl_xor(a0.x, o); a0.y += __shfl_xor(a0.y, o);
    a0.z += __shfl_xor(a0.z, o); a0.w += __shfl_xor(a0.w, o);
    a1.x += __shfl_xor(a1.x, o); a1.y += __shfl_xor(a1.y, o);
    a1.z += __shfl_xor(a1.z, o); a1.w += __shfl_xor(a1.w, o);
  }
  if (g == 0) {
    *(float4*)&AGG[(size_t)node * 64 + gl * 8]     = a0;
    *(float4*)&AGG[(size_t)node * 64 + gl * 8 + 4] = a1;
  }
}

extern "C" void kernel_launch(void* const* d_in, const int* in_sizes, int n_in,
                              void* d_out, int out_size, void* d_ws, size_t ws_size,
                              hipStream_t stream) {
  const int N = in_sizes[0] / IN_C;
  const int E = in_sizes[1] / 2;
  const int* ei  = (const int*)d_in[1];
  const int* src = ei;
  const int* dst = ei + E;
  const int bdiv = (N + NB - 1) / NB;

  char* wsb = (char*)d_ws;
  size_t o = 0;
  auto alloc = [&](size_t elems) { void* p = wsb + o; o += ((elems + 3) & ~3ull) * 4; return p; };
  int*   FLAG   = (int*)alloc(16);
  float* WF     = (float*)alloc(60000);
  int*   CNT    = (int*)alloc((size_t)NB * N);
  int*   OFF    = (int*)alloc((size_t)NB * N + 1);
  int*   CUR    = (int*)alloc((size_t)NB * N);
  int*   PART   = (int*)alloc(256);
  int2*  DL     = (int2*)alloc((size_t)E * 2);
  float* EV     = (float*)alloc(E);
  float* DEN    = (float*)alloc(N);
  uint4* XLB    = (uint4*)alloc((size_t)N * 32);
  uint4* XLN    = (uint4*)alloc((size_t)N * 32);
  uint4* XRNB   = (uint4*)alloc((size_t)N * 32);
  float* bufA   = (float*)alloc((size_t)N * 128);  // XF / OUTF
  float* bufB   = (float*)alloc((size_t)N * 128);  // H0 -> B1 | B2

  float* XF  = bufA;
  float* H0  = bufB;
  float* B1  = bufB;
  float* B2  = bufB + (size_t)N * 64;

  dim3 blk(256);
  auto nblk = [](long total, int per) { return dim3((unsigned)((total + per - 1) / per)); };

  // ---- dtype detect + convert ----
  detect_k<<<1, blk, 0, stream>>>((const unsigned short*)d_in[0], FLAG);
  cvt_k<<<nblk((long)N * 128, 256), blk, 0, stream>>>(d_in[0], XF, N * 128, FLAG);
  WArgs wa;
  int wtot = 0;
  float* wp[16];
  for (int i = 2; i < 16; i++) {
    wa.p[i - 2] = d_in[i];
    wa.off[i - 2] = wtot;
    wp[i] = WF + wtot;
    wtot += in_sizes[i];
  }
  wa.off[14] = wtot;
  cvtw_k<<<nblk(wtot, 256), blk, 0, stream>>>(wa, WF, FLAG, wtot);
  const float *W_in = wp[2], *b_in = wp[3], *Wl1 = wp[4], *Wr1 = wp[5],
              *bias1 = wp[6], *Wc1 = wp[7], *Wl2 = wp[8], *Wr2 = wp[9],
              *bias2 = wp[10], *Wc2 = wp[11], *W3 = wp[12], *b3 = wp[13],
              *W4 = wp[14], *b4 = wp[15];

  // ---- bucketed CSR build ----
  hipMemsetAsync(CNT, 0, sizeof(int) * (size_t)NB * N, stream);
  count_k<<<dim3(2048), blk, 0, stream>>>(src, dst, CNT, E, N, bdiv);
  {
    int nkeys = NB * N;
    int nb = (nkeys + 2047) / 2048;
    scan_local_k<<<dim3(nb), blk, 0, stream>>>(CNT, OFF, PART, nkeys);
    scan_add_k<<<dim3(nb), blk, 0, stream>>>(OFF, CUR, PART, nb, nkeys);
  }
  fill_k<<<dim3(2048), blk, 0, stream>>>(src, dst, CUR, DL, E, N, bdiv);

  // h0 = leaky(x @ W_in + b_in)
  lin_k<128, 128, 8, 1, false, true, 0>
      <<<nblk(N, 64), blk, 0, stream>>>(XF, W_in, nullptr, b_in, H0, nullptr, N);

  // ---- GAT layer 1 ----
  lin_k<128, 64, 4, 0, false, false, 4>
      <<<nblk(N, 64), blk, 0, stream>>>(H0, Wl1, nullptr, nullptr, (float*)XLB, (float*)XLN, N);
  lin_k<128, 64, 4, 0, false, false, 1>
      <<<nblk(N, 64), blk, 0, stream>>>(H0, Wr1, nullptr, nullptr, (float*)XRNB, nullptr, N);
  hipMemsetAsync(DEN, 0, sizeof(float) * (size_t)N, stream);
  gat_pre_k<<<dim3(2048), blk, 0, stream>>>(XLN, XRNB, DL, EV, DEN, E);
  gat_dst_k<<<nblk(N, 4), blk, 0, stream>>>(XLB, EV, DEN, OFF, DL, B1, N);
  lin_k<64, 64, 8, 1, true, false, 0>
      <<<nblk(N, 128), blk, 0, stream>>>(B1, Wc1, bias1, nullptr, B1, nullptr, N);

  // ---- GAT layer 2 ----
  lin_k<64, 64, 8, 0, false, false, 4>
      <<<nblk(N, 128), blk, 0, stream>>>(B1, Wl2, nullptr, nullptr, (float*)XLB, (float*)XLN, N);
  lin_k<64, 64, 8, 0, false, false, 1>
      <<<nblk(N, 128), blk, 0, stream>>>(B1, Wr2, nullptr, nullptr, (float*)XRNB, nullptr, N);
  hipMemsetAsync(DEN, 0, sizeof(float) * (size_t)N, stream);
  gat_pre_k<<<dim3(2048), blk, 0, stream>>>(XLN, XRNB, DL, EV, DEN, E);
  gat_dst_k<<<nblk(N, 4), blk, 0, stream>>>(XLB, EV, DEN, OFF, DL, B2, N);
  lin_k<64, 64, 8, 1, true, false, 0>
      <<<nblk(N, 128), blk, 0, stream>>>(B2, Wc2, bias2, nullptr, B2, nullptr, N);

  // ---- head ----
  lin_k<64, 64, 8, 2, false, true, 0>
      <<<nblk(N, 128), blk, 0, stream>>>(B2, W3, nullptr, b3, B1, nullptr, N);
  lin_k<64, 32, 4, 0, false, true, 0>
      <<<nblk(N, 128), blk, 0, stream>>>(B1, W4, nullptr, b4, bufA, nullptr, N);
  out_k<<<nblk((long)N * 32, 256), blk, 0, stream>>>(bufA, d_out, N * 32, FLAG);
}